// Round 2
// baseline (468.923 us; speedup 1.0000x reference)
//
#include <hip/hip_runtime.h>
#include <hip/hip_bf16.h>

#define B_    32
#define C_    128
#define H_    56
#define W_    56
#define OUT_  256
#define K_    4
#define HID_  64
#define HW_   (H_*W_)        // 3136
#define KV_   (C_*9)         // 1152
#define PH_   58
#define PW_   58
#define PP_   (PH_*PW_)      // 3364 padded pixels per sample

typedef __attribute__((ext_vector_type(8))) short short8_t;   // 8 x bf16
typedef __attribute__((ext_vector_type(4))) float float4_t;

typedef __hip_bfloat16 bf16;

__device__ __forceinline__ short f2bf(float v) {
    union { bf16 h; short s; } u; u.h = __float2bfloat16(v); return u.s;
}

// ---------------------------------------------------------------------------
// Kernel 1: fused  x -> zero-padded xTp[b][58*58][c] (bf16)  +  global avg pool
// (pooled must be zeroed before launch; accumulated with atomics)
// ---------------------------------------------------------------------------
__global__ __launch_bounds__(256) void dc_xt(const float* __restrict__ x,
                                             short* __restrict__ xTp,
                                             float* __restrict__ pooled) {
    int b = blockIdx.y, n0 = blockIdx.x * 128;   // 27 x-blocks cover 3456 >= 3364
    __shared__ short t[C_][130];
    int lane = threadIdx.x & 63;
    for (int i = threadIdx.x; i < C_*128; i += 256) {
        int c = i >> 7, nn = i & 127;            // c is wave-uniform per iteration
        int pp = n0 + nn;
        int py = pp / PW_, px = pp - py*PW_;
        bool valid = (pp < PP_) & (py >= 1) & (py <= H_) & (px >= 1) & (px <= W_);
        float v = valid ? x[((size_t)b*C_ + c)*HW_ + (py-1)*W_ + (px-1)] : 0.f;
        t[c][nn] = f2bf(v);
        // pool: wave-reduce v (c uniform across the wave here)
        float s = v;
        for (int off = 32; off > 0; off >>= 1) s += __shfl_down(s, off, 64);
        if (lane == 0 && s != 0.f) atomicAdd(&pooled[b*C_ + c], s);
    }
    __syncthreads();
    for (int i = threadIdx.x; i < 64*128; i += 256) {
        int nn = i >> 6, c2 = (i & 63) * 2;
        int pp = n0 + nn;
        if (pp < PP_) {
            union { unsigned short u[2]; unsigned v; } pk;
            pk.u[0] = (unsigned short)t[c2][nn];
            pk.u[1] = (unsigned short)t[c2+1][nn];
            *(unsigned*)&xTp[((size_t)b*PP_ + pp)*C_ + c2] = pk.v;
        }
    }
}

// ---------------------------------------------------------------------------
// Kernel 2: attn = softmax(relu((pooled/HW)@fc1^T)@fc2^T)
// ---------------------------------------------------------------------------
__global__ __launch_bounds__(64) void dc_attn(const float* __restrict__ pooled,
                                              const float* __restrict__ fc1w,
                                              const float* __restrict__ fc1b,
                                              const float* __restrict__ fc2w,
                                              const float* __restrict__ fc2b,
                                              float* __restrict__ attn) {
    int b = blockIdx.x, h = threadIdx.x;
    __shared__ float pl[C_];
    __shared__ float hdn[HID_];
    __shared__ float logit[K_];
    pl[h]      = pooled[b*C_ + h]      * (1.0f / HW_);
    pl[h + 64] = pooled[b*C_ + 64 + h] * (1.0f / HW_);
    __syncthreads();
    float s = fc1b[h];
    #pragma unroll 8
    for (int c = 0; c < C_; ++c) s += pl[c] * fc1w[h*C_ + c];
    hdn[h] = fmaxf(s, 0.f);
    __syncthreads();
    if (h < K_) {
        float t = fc2b[h];
        #pragma unroll 8
        for (int j = 0; j < HID_; ++j) t += hdn[j] * fc2w[h*HID_ + j];
        logit[h] = t;
    }
    __syncthreads();
    if (h == 0) {
        float m = fmaxf(fmaxf(logit[0], logit[1]), fmaxf(logit[2], logit[3]));
        float e0 = __expf(logit[0]-m), e1 = __expf(logit[1]-m);
        float e2 = __expf(logit[2]-m), e3 = __expf(logit[3]-m);
        float inv = 1.0f / (e0+e1+e2+e3);
        attn[b*K_+0]=e0*inv; attn[b*K_+1]=e1*inv;
        attn[b*K_+2]=e2*inv; attn[b*K_+3]=e3*inv;
    }
}

// ---------------------------------------------------------------------------
// Kernel 3: weight synthesis  Ws[b][o][k=tap*128+c] (bf16)
// grid (OUT_, 4): block = (o, group of 8 samples); bank row staged in LDS once.
// ---------------------------------------------------------------------------
__global__ __launch_bounds__(256) void dc_wsynth(const float* __restrict__ bank,
                                                 const float* __restrict__ attn,
                                                 bf16* __restrict__ Ws) {
    int o = blockIdx.x;
    int b0 = blockIdx.y * 8;
    __shared__ float wb[4*KV_];
    for (int i = threadIdx.x; i < 4*KV_; i += 256) {
        int kk = i / KV_, r = i - kk*KV_;
        wb[i] = bank[((size_t)kk*OUT_ + o)*KV_ + r];
    }
    __syncthreads();
    for (int bi = 0; bi < 8; ++bi) {
        int b = b0 + bi;
        float a0 = attn[b*K_+0], a1 = attn[b*K_+1];
        float a2 = attn[b*K_+2], a3 = attn[b*K_+3];
        unsigned* dst = (unsigned*)&Ws[((size_t)b*OUT_ + o)*KV_];
        for (int ii = threadIdx.x; ii < KV_/2; ii += 256) {
            int i0 = 2*ii;
            int tap0 = i0 >> 7, c0 = i0 & 127;
            int i1 = i0 + 1;
            int tap1 = i1 >> 7, c1 = i1 & 127;
            float v0 = a0*wb[c0*9+tap0] + a1*wb[KV_+c0*9+tap0]
                     + a2*wb[2*KV_+c0*9+tap0] + a3*wb[3*KV_+c0*9+tap0];
            float v1 = a0*wb[c1*9+tap1] + a1*wb[KV_+c1*9+tap1]
                     + a2*wb[2*KV_+c1*9+tap1] + a3*wb[3*KV_+c1*9+tap1];
            union { unsigned short u[2]; unsigned v; } pk;
            pk.u[0] = (unsigned short)f2bf(v0);
            pk.u[1] = (unsigned short)f2bf(v1);
            dst[ii] = pk.v;
        }
    }
}

// ---------------------------------------------------------------------------
// Kernel 4: ZERO-LDS direct-fragment implicit GEMM.
//   C[b][m][n] = sum_{tap,c} Ws[b][m][tap*128+c] * xTp[b][pad(n)+doffp(tap)][c]
// Both MFMA operands are loaded straight from global memory in fragment
// order: each lane's A fragment is 16 contiguous bytes at
// Ws[row(l16)][tap*128 + kq*32 + quad*8]; the 4 quads of a row cover one
// full 64B cacheline (no over-fetch). Same for B from xTp. No LDS, no
// __syncthreads -- waves free-run, so L2 latency (~200cyc) hides under the
// other waves' MFMA issue with no global drain point. A/B panels are
// L2-resident per XCD thanks to the bijective chunk swizzle (FETCH ~31MB
// measured in round 1).
// Block 128m x 128n, 4 waves 2x2 (64x64 each). 1600 flat blocks.
// ---------------------------------------------------------------------------
__global__ __launch_bounds__(256, 3) void dc_gemm(const short* __restrict__ Ws,
                                                  const short* __restrict__ xTp,
                                                  float* __restrict__ out) {
    // ---- bijective XCD swizzle over the flat 1600-block grid ----
    const int nwg = 25 * 2 * B_;            // 1600
    const int cpx = nwg >> 3;               // 200 blocks per XCD chunk
    int orig = blockIdx.x;
    int swz  = (orig & 7) * cpx + (orig >> 3);
    const int bx  = swz % 25;               // n-block (fastest within chunk)
    const int byz = swz / 25;
    const int by  = byz & 1;                // m-block
    const int b   = byz >> 1;               // sample

    const int m0 = by * 128;
    const int n0 = bx * 128;
    const int tid  = threadIdx.x;
    const int lane = tid & 63;
    const int wv   = tid >> 6;
    const int wm   = wv & 1, wn = wv >> 1;
    const int l16  = lane & 15, quad = lane >> 4;

    // per-lane fragment base pointers (same element mapping the LDS-staged
    // version produced, just without the LDS round-trip)
    const short* aB[4];
    #pragma unroll
    for (int mi = 0; mi < 4; ++mi) {
        int row = m0 + wm*64 + mi*16 + l16;
        aB[mi] = Ws + ((size_t)b*OUT_ + row)*KV_ + quad*8;
    }
    const short* bB[4];
    int nidx[4];
    #pragma unroll
    for (int ni = 0; ni < 4; ++ni) {
        int n = n0 + wn*64 + ni*16 + l16;
        nidx[ni] = n;
        int idc = min(n, HW_ - 1);
        int y = idc / W_, xx = idc - y*W_;
        int pbc = (y + 1)*PW_ + (xx + 1);
        bB[ni] = xTp + ((size_t)b*PP_ + pbc)*C_ + quad*8;
    }

    float4_t acc[4][4];
    #pragma unroll
    for (int mi = 0; mi < 4; ++mi)
        #pragma unroll
        for (int ni = 0; ni < 4; ++ni)
            acc[mi][ni] = (float4_t){0.f, 0.f, 0.f, 0.f};

    #pragma unroll
    for (int tap = 0; tap < 9; ++tap) {
        const int ty = tap / 3, tx = tap - 3*ty;
        const int doff = ((ty - 1)*PW_ + (tx - 1)) * C_;   // B row shift (shorts)
        #pragma unroll
        for (int kq = 0; kq < 4; ++kq) {    // 4 k-slices of 32 within tap's 128
            short8_t af[4], bf[4];
            #pragma unroll
            for (int mi = 0; mi < 4; ++mi)
                af[mi] = *(const short8_t*)(aB[mi] + tap*128 + kq*32);
            #pragma unroll
            for (int ni = 0; ni < 4; ++ni)
                bf[ni] = *(const short8_t*)(bB[ni] + doff + kq*32);
            #pragma unroll
            for (int mi = 0; mi < 4; ++mi)
                #pragma unroll
                for (int ni = 0; ni < 4; ++ni)
                    acc[mi][ni] = __builtin_amdgcn_mfma_f32_16x16x32_bf16(
                        af[mi], bf[ni], acc[mi][ni], 0, 0, 0);
        }
    }

    // Epilogue: D[m = quad*4 + reg][n = l16] per 16x16 tile
    const size_t obase = (size_t)b * OUT_ * HW_;
    #pragma unroll
    for (int mi = 0; mi < 4; ++mi) {
        int m = m0 + wm*64 + mi*16 + quad*4;
        #pragma unroll
        for (int ni = 0; ni < 4; ++ni) {
            int n = nidx[ni];
            if (n < HW_) {
                float* op = out + obase + (size_t)m * HW_ + n;
                #pragma unroll
                for (int r = 0; r < 4; ++r)
                    op[(size_t)r * HW_] = acc[mi][ni][r];
            }
        }
    }
}

// ---------------------------------------------------------------------------
extern "C" void kernel_launch(void* const* d_in, const int* in_sizes, int n_in,
                              void* d_out, int out_size, void* d_ws, size_t ws_size,
                              hipStream_t stream) {
    const float* x    = (const float*)d_in[0];
    const float* bank = (const float*)d_in[1];
    const float* fc1w = (const float*)d_in[2];
    const float* fc1b = (const float*)d_in[3];
    const float* fc2w = (const float*)d_in[4];
    const float* fc2b = (const float*)d_in[5];
    float* out = (float*)d_out;

    char* ws = (char*)d_ws;
    float* pooled = (float*)ws;                          // 16 KB (zeroed below)
    float* attn   = (float*)(ws + 16*1024);              // 512 B
    bf16*  Ws     = (bf16*) (ws + 32*1024);              // 18,874,368 B
    short* xTp    = (short*)(ws + 32*1024 + 18874368);   // 27,557,888 B

    hipMemsetAsync(pooled, 0, B_*C_*sizeof(float), stream);
    dc_xt    <<<dim3(27, B_), 256, 0, stream>>>(x, xTp, pooled);
    dc_attn  <<<B_,     64, 0, stream>>>(pooled, fc1w, fc1b, fc2w, fc2b, attn);
    dc_wsynth<<<dim3(OUT_, 4), 256, 0, stream>>>(bank, attn, Ws);
    dc_gemm  <<<dim3(1600), 256, 0, stream>>>((const short*)Ws, xTp, out);
}

// Round 3
// 322.933 us; speedup vs baseline: 1.4521x; 1.4521x over previous
//
#include <hip/hip_runtime.h>
#include <hip/hip_bf16.h>

#define B_    32
#define C_    128
#define H_    56
#define W_    56
#define OUT_  256
#define K_    4
#define HID_  64
#define HW_   (H_*W_)        // 3136
#define KV_   (C_*9)         // 1152
#define PH_   58
#define PW_   58
#define PP_   (PH_*PW_)      // 3364 padded pixels per sample

typedef __attribute__((ext_vector_type(8))) short short8_t;   // 8 x bf16
typedef __attribute__((ext_vector_type(4))) float float4_t;

typedef __hip_bfloat16 bf16;

__device__ __forceinline__ short f2bf(float v) {
    union { bf16 h; short s; } u; u.h = __float2bfloat16(v); return u.s;
}

typedef __attribute__((address_space(1))) const unsigned int* gas_t;
typedef __attribute__((address_space(3))) unsigned int* las_t;

// async global->LDS, 16 B per lane; LDS dest = wave-uniform base + lane*16
__device__ __forceinline__ void gl_lds16(const short* g, short* l) {
    __builtin_amdgcn_global_load_lds((gas_t)(const void*)g, (las_t)(void*)l, 16, 0, 0);
}

// ---------------------------------------------------------------------------
// Kernel 0: global avg pool (sums; dc_attn divides by HW).
// One block per (b,c): coalesced float4 reads, per-thread serial sum, one
// wave reduce, no atomics, no memset. Replaces the per-iteration shfl+atomic
// reduce that was welded into dc_xt.
// ---------------------------------------------------------------------------
__global__ __launch_bounds__(256) void dc_pool(const float* __restrict__ x,
                                               float* __restrict__ pooled) {
    int bc = blockIdx.x;                       // b*C_ + c
    const float4_t* xp = (const float4_t*)(x + (size_t)bc * HW_);
    float s = 0.f;
    for (int j = threadIdx.x; j < HW_/4; j += 256) {   // 784 float4
        float4_t v = xp[j];
        s += v[0] + v[1] + v[2] + v[3];
    }
    #pragma unroll
    for (int off = 32; off; off >>= 1) s += __shfl_down(s, off, 64);
    __shared__ float ps[4];
    if ((threadIdx.x & 63) == 0) ps[threadIdx.x >> 6] = s;
    __syncthreads();
    if (threadIdx.x == 0) pooled[bc] = ps[0] + ps[1] + ps[2] + ps[3];
}

// ---------------------------------------------------------------------------
// Kernel 1: pure pad-transpose  x -> zero-padded xTp[b][58*58][c] (bf16).
// (pooling removed -> no shfl/atomic in the inner loop)
// ---------------------------------------------------------------------------
__global__ __launch_bounds__(256) void dc_xt(const float* __restrict__ x,
                                             short* __restrict__ xTp) {
    int b = blockIdx.y, n0 = blockIdx.x * 128;   // 27 x-blocks cover 3456 >= 3364
    __shared__ short t[C_][130];
    for (int i = threadIdx.x; i < C_*128; i += 256) {
        int c = i >> 7, nn = i & 127;
        int pp = n0 + nn;
        int py = pp / PW_, px = pp - py*PW_;
        bool valid = (pp < PP_) & (py >= 1) & (py <= H_) & (px >= 1) & (px <= W_);
        float v = valid ? x[((size_t)b*C_ + c)*HW_ + (py-1)*W_ + (px-1)] : 0.f;
        t[c][nn] = f2bf(v);
    }
    __syncthreads();
    typedef __attribute__((ext_vector_type(2))) unsigned int uint2_t;
    for (int i = threadIdx.x; i < 32*128; i += 256) {
        int nn = i >> 5, c4 = (i & 31) * 4;
        int pp = n0 + nn;
        if (pp < PP_) {
            union { unsigned short u[4]; uint2_t v; } pk;
            pk.u[0] = (unsigned short)t[c4  ][nn];
            pk.u[1] = (unsigned short)t[c4+1][nn];
            pk.u[2] = (unsigned short)t[c4+2][nn];
            pk.u[3] = (unsigned short)t[c4+3][nn];
            *(uint2_t*)&xTp[((size_t)b*PP_ + pp)*C_ + c4] = pk.v;
        }
    }
}

// ---------------------------------------------------------------------------
// Kernel 2: attn = softmax(relu((pooled/HW)@fc1^T)@fc2^T)
// ---------------------------------------------------------------------------
__global__ __launch_bounds__(64) void dc_attn(const float* __restrict__ pooled,
                                              const float* __restrict__ fc1w,
                                              const float* __restrict__ fc1b,
                                              const float* __restrict__ fc2w,
                                              const float* __restrict__ fc2b,
                                              float* __restrict__ attn) {
    int b = blockIdx.x, h = threadIdx.x;
    __shared__ float pl[C_];
    __shared__ float hdn[HID_];
    __shared__ float logit[K_];
    pl[h]      = pooled[b*C_ + h]      * (1.0f / HW_);
    pl[h + 64] = pooled[b*C_ + 64 + h] * (1.0f / HW_);
    __syncthreads();
    float s = fc1b[h];
    #pragma unroll 8
    for (int c = 0; c < C_; ++c) s += pl[c] * fc1w[h*C_ + c];
    hdn[h] = fmaxf(s, 0.f);
    __syncthreads();
    if (h < K_) {
        float t = fc2b[h];
        #pragma unroll 8
        for (int j = 0; j < HID_; ++j) t += hdn[j] * fc2w[h*HID_ + j];
        logit[h] = t;
    }
    __syncthreads();
    if (h == 0) {
        float m = fmaxf(fmaxf(logit[0], logit[1]), fmaxf(logit[2], logit[3]));
        float e0 = __expf(logit[0]-m), e1 = __expf(logit[1]-m);
        float e2 = __expf(logit[2]-m), e3 = __expf(logit[3]-m);
        float inv = 1.0f / (e0+e1+e2+e3);
        attn[b*K_+0]=e0*inv; attn[b*K_+1]=e1*inv;
        attn[b*K_+2]=e2*inv; attn[b*K_+3]=e3*inv;
    }
}

// ---------------------------------------------------------------------------
// Kernel 3: weight synthesis  Ws[b][o][k=tap*128+c] (bf16)
// grid (OUT_, 4): block = (o, group of 8 samples); bank row staged in LDS once.
// ---------------------------------------------------------------------------
__global__ __launch_bounds__(256) void dc_wsynth(const float* __restrict__ bank,
                                                 const float* __restrict__ attn,
                                                 bf16* __restrict__ Ws) {
    int o = blockIdx.x;
    int b0 = blockIdx.y * 8;
    __shared__ float wb[4*KV_];
    for (int i = threadIdx.x; i < 4*KV_; i += 256) {
        int kk = i / KV_, r = i - kk*KV_;
        wb[i] = bank[((size_t)kk*OUT_ + o)*KV_ + r];
    }
    __syncthreads();
    for (int bi = 0; bi < 8; ++bi) {
        int b = b0 + bi;
        float a0 = attn[b*K_+0], a1 = attn[b*K_+1];
        float a2 = attn[b*K_+2], a3 = attn[b*K_+3];
        unsigned* dst = (unsigned*)&Ws[((size_t)b*OUT_ + o)*KV_];
        for (int ii = threadIdx.x; ii < KV_/2; ii += 256) {
            int i0 = 2*ii;
            int tap0 = i0 >> 7, c0 = i0 & 127;
            int i1 = i0 + 1;
            int tap1 = i1 >> 7, c1 = i1 & 127;
            float v0 = a0*wb[c0*9+tap0] + a1*wb[KV_+c0*9+tap0]
                     + a2*wb[2*KV_+c0*9+tap0] + a3*wb[3*KV_+c0*9+tap0];
            float v1 = a0*wb[c1*9+tap1] + a1*wb[KV_+c1*9+tap1]
                     + a2*wb[2*KV_+c1*9+tap1] + a3*wb[3*KV_+c1*9+tap1];
            union { unsigned short u[2]; unsigned v; } pk;
            pk.u[0] = (unsigned short)f2bf(v0);
            pk.u[1] = (unsigned short)f2bf(v1);
            dst[ii] = pk.v;
        }
    }
}

// ---------------------------------------------------------------------------
// Kernel 4: LDS-staged implicit GEMM (m97 structure, BK=64) — exact round-0
// version (measured 150 us; both the dbuf variant and the zero-LDS variant
// regressed: 192 / 260 us).
// ---------------------------------------------------------------------------
__global__ __launch_bounds__(256) void dc_gemm(const short* __restrict__ Ws,
                                               const short* __restrict__ xTp,
                                               float* __restrict__ out) {
    const int b  = blockIdx.z;
    const int m0 = blockIdx.y * 128;
    const int n0 = blockIdx.x * 128;
    const int tid  = threadIdx.x;
    const int lane = tid & 63;
    const int wv   = tid >> 6;
    const int wm   = wv & 1, wn = wv >> 1;
    const int l16  = lane & 15, quad = lane >> 4;

    __shared__ short lA[128*64];   // 16 KB
    __shared__ short lB[128*64];   // 16 KB

    // --- staging source pointers: wave wv stages segments t = 4*wv + j ---
    const short* aG[4];
    const short* bG[4];
    short* aL[4];
    short* bL[4];
    #pragma unroll
    for (int j = 0; j < 4; ++j) {
        int t = 4*wv + j;
        int row = (t >> 1) * 16 + l16;
        int kq  = t & 1;
        aG[j] = Ws + ((size_t)b*OUT_ + m0 + row)*KV_ + kq*32 + quad*8;
        int n = n0 + row;
        int idc = min(n, HW_ - 1);
        int y = idc / W_, xx2 = idc - y * W_;
        int pbc = (y + 1) * PW_ + (xx2 + 1);
        bG[j] = xTp + ((size_t)b*PP_ + pbc)*C_ + kq*32 + quad*8;
        aL[j] = lA + t*512;
        bL[j] = lB + t*512;
    }

    int nidx[4];
    #pragma unroll
    for (int ni = 0; ni < 4; ++ni)
        nidx[ni] = n0 + wn*64 + ni*16 + l16;

    float4_t acc[4][4];
    #pragma unroll
    for (int mi = 0; mi < 4; ++mi)
        #pragma unroll
        for (int ni = 0; ni < 4; ++ni)
            acc[mi][ni] = (float4_t){0.f, 0.f, 0.f, 0.f};

    for (int tap = 0; tap < 9; ++tap) {
        int ty = tap / 3, tx = tap - 3*ty;
        int doff = (ty - 1) * PW_ + (tx - 1);
        #pragma unroll
        for (int half = 0; half < 2; ++half) {
            const int kk = tap*128 + half*64;   // A column base
            const int cc = half*64;             // B column base
            #pragma unroll
            for (int j = 0; j < 4; ++j) {
                gl_lds16(aG[j] + kk, aL[j]);
                gl_lds16(bG[j] + doff*C_ + cc, bL[j]);
            }
            __syncthreads();                    // drains vmcnt(0), publishes LDS
            #pragma unroll
            for (int kq = 0; kq < 2; ++kq) {
                short8_t af[4], bf[4];
                #pragma unroll
                for (int mi = 0; mi < 4; ++mi)
                    af[mi] = *(const short8_t*)(lA + ((wm*4+mi)*2 + kq)*512 + lane*8);
                #pragma unroll
                for (int ni = 0; ni < 4; ++ni)
                    bf[ni] = *(const short8_t*)(lB + ((wn*4+ni)*2 + kq)*512 + lane*8);
                #pragma unroll
                for (int mi = 0; mi < 4; ++mi)
                    #pragma unroll
                    for (int ni = 0; ni < 4; ++ni)
                        acc[mi][ni] = __builtin_amdgcn_mfma_f32_16x16x32_bf16(
                            af[mi], bf[ni], acc[mi][ni], 0, 0, 0);
            }
            __syncthreads();                    // all reads done before next overwrite
        }
    }

    // Epilogue: D[m = quad*4 + reg][n = l16] per 16x16 tile
    const size_t obase = (size_t)b * OUT_ * HW_;
    #pragma unroll
    for (int mi = 0; mi < 4; ++mi) {
        int m = m0 + wm*64 + mi*16 + quad*4;
        #pragma unroll
        for (int ni = 0; ni < 4; ++ni) {
            int n = nidx[ni];
            if (n < HW_) {
                float* op = out + obase + (size_t)m * HW_ + n;
                #pragma unroll
                for (int r = 0; r < 4; ++r)
                    op[(size_t)r * HW_] = acc[mi][ni][r];
            }
        }
    }
}

// ---------------------------------------------------------------------------
extern "C" void kernel_launch(void* const* d_in, const int* in_sizes, int n_in,
                              void* d_out, int out_size, void* d_ws, size_t ws_size,
                              hipStream_t stream) {
    const float* x    = (const float*)d_in[0];
    const float* bank = (const float*)d_in[1];
    const float* fc1w = (const float*)d_in[2];
    const float* fc1b = (const float*)d_in[3];
    const float* fc2w = (const float*)d_in[4];
    const float* fc2b = (const float*)d_in[5];
    float* out = (float*)d_out;

    char* ws = (char*)d_ws;
    float* pooled = (float*)ws;                          // 16 KB
    float* attn   = (float*)(ws + 16*1024);              // 512 B
    bf16*  Ws     = (bf16*) (ws + 32*1024);              // 18,874,368 B
    short* xTp    = (short*)(ws + 32*1024 + 18874368);   // 27,557,888 B

    dc_pool  <<<B_*C_, 256, 0, stream>>>(x, pooled);
    dc_xt    <<<dim3(27, B_), 256, 0, stream>>>(x, xTp);
    dc_attn  <<<B_,     64, 0, stream>>>(pooled, fc1w, fc1b, fc2w, fc2b, attn);
    dc_wsynth<<<dim3(OUT_, 4), 256, 0, stream>>>(bank, attn, Ws);
    dc_gemm  <<<dim3(25, 2, B_), 256, 0, stream>>>((const short*)Ws, xTp, out);
}

// Round 4
// 321.337 us; speedup vs baseline: 1.4593x; 1.0050x over previous
//
#include <hip/hip_runtime.h>
#include <hip/hip_bf16.h>

#define B_    32
#define C_    128
#define H_    56
#define W_    56
#define OUT_  256
#define K_    4
#define HID_  64
#define HW_   (H_*W_)        // 3136
#define KV_   (C_*9)         // 1152
#define PH_   58
#define PW_   58
#define PP_   (PH_*PW_)      // 3364 padded pixels per sample

typedef __attribute__((ext_vector_type(8))) short short8_t;   // 8 x bf16
typedef __attribute__((ext_vector_type(4))) float float4_t;

typedef __hip_bfloat16 bf16;

__device__ __forceinline__ short f2bf(float v) {
    union { bf16 h; short s; } u; u.h = __float2bfloat16(v); return u.s;
}

typedef __attribute__((address_space(1))) const unsigned int* gas_t;
typedef __attribute__((address_space(3))) unsigned int* las_t;

// async global->LDS, 16 B per lane; LDS dest = wave-uniform base + lane*16
__device__ __forceinline__ void gl_lds16(const short* g, short* l) {
    __builtin_amdgcn_global_load_lds((gas_t)(const void*)g, (las_t)(void*)l, 16, 0, 0);
}

// ---------------------------------------------------------------------------
// Kernel 0: global avg pool (sums; dc_attn divides by HW).
// ---------------------------------------------------------------------------
__global__ __launch_bounds__(256) void dc_pool(const float* __restrict__ x,
                                               float* __restrict__ pooled) {
    int bc = blockIdx.x;                       // b*C_ + c
    const float4_t* xp = (const float4_t*)(x + (size_t)bc * HW_);
    float s = 0.f;
    for (int j = threadIdx.x; j < HW_/4; j += 256) {   // 784 float4
        float4_t v = xp[j];
        s += v[0] + v[1] + v[2] + v[3];
    }
    #pragma unroll
    for (int off = 32; off; off >>= 1) s += __shfl_down(s, off, 64);
    __shared__ float ps[4];
    if ((threadIdx.x & 63) == 0) ps[threadIdx.x >> 6] = s;
    __syncthreads();
    if (threadIdx.x == 0) pooled[bc] = ps[0] + ps[1] + ps[2] + ps[3];
}

// ---------------------------------------------------------------------------
// Kernel 1: pure pad-transpose  x -> zero-padded xTp[b][58*58][c] (bf16).
// ---------------------------------------------------------------------------
__global__ __launch_bounds__(256) void dc_xt(const float* __restrict__ x,
                                             short* __restrict__ xTp) {
    int b = blockIdx.y, n0 = blockIdx.x * 128;   // 27 x-blocks cover 3456 >= 3364
    __shared__ short t[C_][130];
    for (int i = threadIdx.x; i < C_*128; i += 256) {
        int c = i >> 7, nn = i & 127;
        int pp = n0 + nn;
        int py = pp / PW_, px = pp - py*PW_;
        bool valid = (pp < PP_) & (py >= 1) & (py <= H_) & (px >= 1) & (px <= W_);
        float v = valid ? x[((size_t)b*C_ + c)*HW_ + (py-1)*W_ + (px-1)] : 0.f;
        t[c][nn] = f2bf(v);
    }
    __syncthreads();
    typedef __attribute__((ext_vector_type(2))) unsigned int uint2_t;
    for (int i = threadIdx.x; i < 32*128; i += 256) {
        int nn = i >> 5, c4 = (i & 31) * 4;
        int pp = n0 + nn;
        if (pp < PP_) {
            union { unsigned short u[4]; uint2_t v; } pk;
            pk.u[0] = (unsigned short)t[c4  ][nn];
            pk.u[1] = (unsigned short)t[c4+1][nn];
            pk.u[2] = (unsigned short)t[c4+2][nn];
            pk.u[3] = (unsigned short)t[c4+3][nn];
            *(uint2_t*)&xTp[((size_t)b*PP_ + pp)*C_ + c4] = pk.v;
        }
    }
}

// ---------------------------------------------------------------------------
// Kernel 2: attn = softmax(relu((pooled/HW)@fc1^T)@fc2^T)
// ---------------------------------------------------------------------------
__global__ __launch_bounds__(64) void dc_attn(const float* __restrict__ pooled,
                                              const float* __restrict__ fc1w,
                                              const float* __restrict__ fc1b,
                                              const float* __restrict__ fc2w,
                                              const float* __restrict__ fc2b,
                                              float* __restrict__ attn) {
    int b = blockIdx.x, h = threadIdx.x;
    __shared__ float pl[C_];
    __shared__ float hdn[HID_];
    __shared__ float logit[K_];
    pl[h]      = pooled[b*C_ + h]      * (1.0f / HW_);
    pl[h + 64] = pooled[b*C_ + 64 + h] * (1.0f / HW_);
    __syncthreads();
    float s = fc1b[h];
    #pragma unroll 8
    for (int c = 0; c < C_; ++c) s += pl[c] * fc1w[h*C_ + c];
    hdn[h] = fmaxf(s, 0.f);
    __syncthreads();
    if (h < K_) {
        float t = fc2b[h];
        #pragma unroll 8
        for (int j = 0; j < HID_; ++j) t += hdn[j] * fc2w[h*HID_ + j];
        logit[h] = t;
    }
    __syncthreads();
    if (h == 0) {
        float m = fmaxf(fmaxf(logit[0], logit[1]), fmaxf(logit[2], logit[3]));
        float e0 = __expf(logit[0]-m), e1 = __expf(logit[1]-m);
        float e2 = __expf(logit[2]-m), e3 = __expf(logit[3]-m);
        float inv = 1.0f / (e0+e1+e2+e3);
        attn[b*K_+0]=e0*inv; attn[b*K_+1]=e1*inv;
        attn[b*K_+2]=e2*inv; attn[b*K_+3]=e3*inv;
    }
}

// ---------------------------------------------------------------------------
// Kernel 3: weight synthesis  Ws[b][o][k=tap*128+c] (bf16)
// ---------------------------------------------------------------------------
__global__ __launch_bounds__(256) void dc_wsynth(const float* __restrict__ bank,
                                                 const float* __restrict__ attn,
                                                 bf16* __restrict__ Ws) {
    int o = blockIdx.x;
    int b0 = blockIdx.y * 8;
    __shared__ float wb[4*KV_];
    for (int i = threadIdx.x; i < 4*KV_; i += 256) {
        int kk = i / KV_, r = i - kk*KV_;
        wb[i] = bank[((size_t)kk*OUT_ + o)*KV_ + r];
    }
    __syncthreads();
    for (int bi = 0; bi < 8; ++bi) {
        int b = b0 + bi;
        float a0 = attn[b*K_+0], a1 = attn[b*K_+1];
        float a2 = attn[b*K_+2], a3 = attn[b*K_+3];
        unsigned* dst = (unsigned*)&Ws[((size_t)b*OUT_ + o)*KV_];
        for (int ii = threadIdx.x; ii < KV_/2; ii += 256) {
            int i0 = 2*ii;
            int tap0 = i0 >> 7, c0 = i0 & 127;
            int i1 = i0 + 1;
            int tap1 = i1 >> 7, c1 = i1 & 127;
            float v0 = a0*wb[c0*9+tap0] + a1*wb[KV_+c0*9+tap0]
                     + a2*wb[2*KV_+c0*9+tap0] + a3*wb[3*KV_+c0*9+tap0];
            float v1 = a0*wb[c1*9+tap1] + a1*wb[KV_+c1*9+tap1]
                     + a2*wb[2*KV_+c1*9+tap1] + a3*wb[3*KV_+c1*9+tap1];
            union { unsigned short u[2]; unsigned v; } pk;
            pk.u[0] = (unsigned short)f2bf(v0);
            pk.u[1] = (unsigned short)f2bf(v1);
            dst[ii] = pk.v;
        }
    }
}

// ---------------------------------------------------------------------------
// Kernel 4: LDS-staged implicit GEMM, double-buffered at BK=32.
// Key difference vs the two failed variants:
//   - round-1 dbuf (BK=64, 64 KB LDS) lost a resident block/CU -> regressed.
//   - BK=32 dbuf keeps LDS at 32 KB total (same 3 blocks/CU as the 150us
//     baseline) AND prefetches the next 32-k slice before computing the
//     current one, so each barrier's vmcnt(0) drain is covered by ~930 cyc
//     of MFMA+ds_read instead of being fully exposed.
// Per sub-step (36 total: 9 taps x 4 k-slices of 32): each wave issues
// 4 global_load_lds into buf^1, computes buf (8 ds_read_b128 + 16 MFMA),
// one __syncthreads. Mapping is the round-0 proven one (kq2 = half*2+kq
// relabeling; identical accumulation order).
// Flat 1600-block grid + bijective XCD swizzle (FETCH 122->31 MB, round 1).
// ---------------------------------------------------------------------------
__global__ __launch_bounds__(256) void dc_gemm(const short* __restrict__ Ws,
                                               const short* __restrict__ xTp,
                                               float* __restrict__ out) {
    // ---- bijective XCD swizzle over the flat 1600-block grid ----
    int orig = blockIdx.x;
    int swz  = (orig & 7) * 200 + (orig >> 3);   // 1600 % 8 == 0 -> bijective
    const int bx  = swz % 25;                    // n-block
    const int byz = swz / 25;
    const int by  = byz & 1;                     // m-block
    const int b   = byz >> 1;                    // sample

    const int m0 = by * 128;
    const int n0 = bx * 128;
    const int tid  = threadIdx.x;
    const int lane = tid & 63;
    const int wv   = tid >> 6;
    const int wm   = wv & 1, wn = wv >> 1;
    const int l16  = lane & 15, quad = lane >> 4;

    __shared__ short lA[2][4096];   // 2 x 8 KB
    __shared__ short lB[2][4096];   // 2 x 8 KB   (32 KB total, as baseline)

    // wave wv stages regions t = 2*wv + j (j=0,1) for both A and B.
    // Region t holds rows t*16+l16, one 32-k slice; lane offset quad*8 shorts.
    const short* aG[2];
    const short* bG[2];
    int tOff[2];
    #pragma unroll
    for (int j = 0; j < 2; ++j) {
        int t = 2*wv + j;
        int row = t*16 + l16;
        aG[j] = Ws + ((size_t)b*OUT_ + m0 + row)*KV_ + quad*8;
        int n = n0 + row;
        int idc = min(n, HW_ - 1);
        int y = idc / W_, xx2 = idc - y * W_;
        int pbc = (y + 1) * PW_ + (xx2 + 1);
        bG[j] = xTp + ((size_t)b*PP_ + pbc)*C_ + quad*8;
        tOff[j] = t * 512;
    }

    int nidx[4];
    #pragma unroll
    for (int ni = 0; ni < 4; ++ni)
        nidx[ni] = n0 + wn*64 + ni*16 + l16;

    float4_t acc[4][4];
    #pragma unroll
    for (int mi = 0; mi < 4; ++mi)
        #pragma unroll
        for (int ni = 0; ni < 4; ++ni)
            acc[mi][ni] = (float4_t){0.f, 0.f, 0.f, 0.f};

    // stage sub-step ss (= tap*4 + kq2, 36 total) into buffer buf
    auto stage = [&](int ss, int buf) {
        int tap = ss >> 2, kq2 = ss & 3;
        int ty = tap / 3, tx = tap - 3*ty;
        int doff = ((ty - 1) * PW_ + (tx - 1)) * C_;  // B row shift (shorts)
        int ka = tap*128 + kq2*32;                    // A column base
        int cb = kq2*32;                              // B column base
        #pragma unroll
        for (int j = 0; j < 2; ++j) {
            gl_lds16(aG[j] + ka,        &lA[buf][tOff[j]]);
            gl_lds16(bG[j] + doff + cb, &lB[buf][tOff[j]]);
        }
    };

    auto compute = [&](int buf) {
        short8_t af[4], bfr[4];
        #pragma unroll
        for (int mi = 0; mi < 4; ++mi)
            af[mi] = *(const short8_t*)(&lA[buf][(wm*4+mi)*512 + lane*8]);
        #pragma unroll
        for (int ni = 0; ni < 4; ++ni)
            bfr[ni] = *(const short8_t*)(&lB[buf][(wn*4+ni)*512 + lane*8]);
        #pragma unroll
        for (int mi = 0; mi < 4; ++mi)
            #pragma unroll
            for (int ni = 0; ni < 4; ++ni)
                acc[mi][ni] = __builtin_amdgcn_mfma_f32_16x16x32_bf16(
                    af[mi], bfr[ni], acc[mi][ni], 0, 0, 0);
    };

    stage(0, 0);
    __syncthreads();                    // publish sub-step 0
    for (int ss = 0; ss < 36; ++ss) {
        int buf = ss & 1;
        if (ss < 35) stage(ss + 1, buf ^ 1);   // prefetch overlaps compute
        compute(buf);
        __syncthreads();                // vmcnt(0): prefetch landed;
                                        // lgkmcnt(0): this buf's reads done
    }

    // Epilogue: D[m = quad*4 + reg][n = l16] per 16x16 tile
    const size_t obase = (size_t)b * OUT_ * HW_;
    #pragma unroll
    for (int mi = 0; mi < 4; ++mi) {
        int m = m0 + wm*64 + mi*16 + quad*4;
        #pragma unroll
        for (int ni = 0; ni < 4; ++ni) {
            int n = nidx[ni];
            if (n < HW_) {
                float* op = out + obase + (size_t)m * HW_ + n;
                #pragma unroll
                for (int r = 0; r < 4; ++r)
                    op[(size_t)r * HW_] = acc[mi][ni][r];
            }
        }
    }
}

// ---------------------------------------------------------------------------
extern "C" void kernel_launch(void* const* d_in, const int* in_sizes, int n_in,
                              void* d_out, int out_size, void* d_ws, size_t ws_size,
                              hipStream_t stream) {
    const float* x    = (const float*)d_in[0];
    const float* bank = (const float*)d_in[1];
    const float* fc1w = (const float*)d_in[2];
    const float* fc1b = (const float*)d_in[3];
    const float* fc2w = (const float*)d_in[4];
    const float* fc2b = (const float*)d_in[5];
    float* out = (float*)d_out;

    char* ws = (char*)d_ws;
    float* pooled = (float*)ws;                          // 16 KB
    float* attn   = (float*)(ws + 16*1024);              // 512 B
    bf16*  Ws     = (bf16*) (ws + 32*1024);              // 18,874,368 B
    short* xTp    = (short*)(ws + 32*1024 + 18874368);   // 27,557,888 B

    dc_pool  <<<B_*C_, 256, 0, stream>>>(x, pooled);
    dc_xt    <<<dim3(27, B_), 256, 0, stream>>>(x, xTp);
    dc_attn  <<<B_,     64, 0, stream>>>(pooled, fc1w, fc1b, fc2w, fc2b, attn);
    dc_wsynth<<<dim3(OUT_, 4), 256, 0, stream>>>(bank, attn, Ws);
    dc_gemm  <<<dim3(1600), 256, 0, stream>>>((const short*)Ws, xTp, out);
}

// Round 5
// 320.413 us; speedup vs baseline: 1.4635x; 1.0029x over previous
//
#include <hip/hip_runtime.h>
#include <hip/hip_bf16.h>

#define B_    32
#define C_    128
#define H_    56
#define W_    56
#define OUT_  256
#define K_    4
#define HID_  64
#define HW_   (H_*W_)        // 3136
#define KV_   (C_*9)         // 1152
#define PH_   58
#define PW_   58
#define PP_   (PH_*PW_)      // 3364 padded pixels per sample

typedef __attribute__((ext_vector_type(8))) short short8_t;   // 8 x bf16
typedef __attribute__((ext_vector_type(4))) float float4_t;

typedef __hip_bfloat16 bf16;

__device__ __forceinline__ short f2bf(float v) {
    union { bf16 h; short s; } u; u.h = __float2bfloat16(v); return u.s;
}

typedef __attribute__((address_space(1))) const unsigned int* gas_t;
typedef __attribute__((address_space(3))) unsigned int* las_t;

// async global->LDS, 16 B per lane; LDS dest = wave-uniform base + lane*16
__device__ __forceinline__ void gl_lds16(const short* g, short* l) {
    __builtin_amdgcn_global_load_lds((gas_t)(const void*)g, (las_t)(void*)l, 16, 0, 0);
}

// ---------------------------------------------------------------------------
// Kernel 0: global avg pool (sums; dc_attn divides by HW).
// ---------------------------------------------------------------------------
__global__ __launch_bounds__(256) void dc_pool(const float* __restrict__ x,
                                               float* __restrict__ pooled) {
    int bc = blockIdx.x;                       // b*C_ + c
    const float4_t* xp = (const float4_t*)(x + (size_t)bc * HW_);
    float s = 0.f;
    for (int j = threadIdx.x; j < HW_/4; j += 256) {   // 784 float4
        float4_t v = xp[j];
        s += v[0] + v[1] + v[2] + v[3];
    }
    #pragma unroll
    for (int off = 32; off; off >>= 1) s += __shfl_down(s, off, 64);
    __shared__ float ps[4];
    if ((threadIdx.x & 63) == 0) ps[threadIdx.x >> 6] = s;
    __syncthreads();
    if (threadIdx.x == 0) pooled[bc] = ps[0] + ps[1] + ps[2] + ps[3];
}

// ---------------------------------------------------------------------------
// Kernel 1: pure pad-transpose  x -> zero-padded xTp[b][58*58][c] (bf16).
// ---------------------------------------------------------------------------
__global__ __launch_bounds__(256) void dc_xt(const float* __restrict__ x,
                                             short* __restrict__ xTp) {
    int b = blockIdx.y, n0 = blockIdx.x * 128;   // 27 x-blocks cover 3456 >= 3364
    __shared__ short t[C_][130];
    for (int i = threadIdx.x; i < C_*128; i += 256) {
        int c = i >> 7, nn = i & 127;
        int pp = n0 + nn;
        int py = pp / PW_, px = pp - py*PW_;
        bool valid = (pp < PP_) & (py >= 1) & (py <= H_) & (px >= 1) & (px <= W_);
        float v = valid ? x[((size_t)b*C_ + c)*HW_ + (py-1)*W_ + (px-1)] : 0.f;
        t[c][nn] = f2bf(v);
    }
    __syncthreads();
    typedef __attribute__((ext_vector_type(2))) unsigned int uint2_t;
    for (int i = threadIdx.x; i < 32*128; i += 256) {
        int nn = i >> 5, c4 = (i & 31) * 4;
        int pp = n0 + nn;
        if (pp < PP_) {
            union { unsigned short u[4]; uint2_t v; } pk;
            pk.u[0] = (unsigned short)t[c4  ][nn];
            pk.u[1] = (unsigned short)t[c4+1][nn];
            pk.u[2] = (unsigned short)t[c4+2][nn];
            pk.u[3] = (unsigned short)t[c4+3][nn];
            *(uint2_t*)&xTp[((size_t)b*PP_ + pp)*C_ + c4] = pk.v;
        }
    }
}

// ---------------------------------------------------------------------------
// Kernel 2: attn = softmax(relu((pooled/HW)@fc1^T)@fc2^T)
// ---------------------------------------------------------------------------
__global__ __launch_bounds__(64) void dc_attn(const float* __restrict__ pooled,
                                              const float* __restrict__ fc1w,
                                              const float* __restrict__ fc1b,
                                              const float* __restrict__ fc2w,
                                              const float* __restrict__ fc2b,
                                              float* __restrict__ attn) {
    int b = blockIdx.x, h = threadIdx.x;
    __shared__ float pl[C_];
    __shared__ float hdn[HID_];
    __shared__ float logit[K_];
    pl[h]      = pooled[b*C_ + h]      * (1.0f / HW_);
    pl[h + 64] = pooled[b*C_ + 64 + h] * (1.0f / HW_);
    __syncthreads();
    float s = fc1b[h];
    #pragma unroll 8
    for (int c = 0; c < C_; ++c) s += pl[c] * fc1w[h*C_ + c];
    hdn[h] = fmaxf(s, 0.f);
    __syncthreads();
    if (h < K_) {
        float t = fc2b[h];
        #pragma unroll 8
        for (int j = 0; j < HID_; ++j) t += hdn[j] * fc2w[h*HID_ + j];
        logit[h] = t;
    }
    __syncthreads();
    if (h == 0) {
        float m = fmaxf(fmaxf(logit[0], logit[1]), fmaxf(logit[2], logit[3]));
        float e0 = __expf(logit[0]-m), e1 = __expf(logit[1]-m);
        float e2 = __expf(logit[2]-m), e3 = __expf(logit[3]-m);
        float inv = 1.0f / (e0+e1+e2+e3);
        attn[b*K_+0]=e0*inv; attn[b*K_+1]=e1*inv;
        attn[b*K_+2]=e2*inv; attn[b*K_+3]=e3*inv;
    }
}

// ---------------------------------------------------------------------------
// Kernel 3: weight synthesis  Ws[b][o][k=tap*128+c] (bf16)
// ---------------------------------------------------------------------------
__global__ __launch_bounds__(256) void dc_wsynth(const float* __restrict__ bank,
                                                 const float* __restrict__ attn,
                                                 bf16* __restrict__ Ws) {
    int o = blockIdx.x;
    int b0 = blockIdx.y * 8;
    __shared__ float wb[4*KV_];
    for (int i = threadIdx.x; i < 4*KV_; i += 256) {
        int kk = i / KV_, r = i - kk*KV_;
        wb[i] = bank[((size_t)kk*OUT_ + o)*KV_ + r];
    }
    __syncthreads();
    for (int bi = 0; bi < 8; ++bi) {
        int b = b0 + bi;
        float a0 = attn[b*K_+0], a1 = attn[b*K_+1];
        float a2 = attn[b*K_+2], a3 = attn[b*K_+3];
        unsigned* dst = (unsigned*)&Ws[((size_t)b*OUT_ + o)*KV_];
        for (int ii = threadIdx.x; ii < KV_/2; ii += 256) {
            int i0 = 2*ii;
            int tap0 = i0 >> 7, c0 = i0 & 127;
            int i1 = i0 + 1;
            int tap1 = i1 >> 7, c1 = i1 & 127;
            float v0 = a0*wb[c0*9+tap0] + a1*wb[KV_+c0*9+tap0]
                     + a2*wb[2*KV_+c0*9+tap0] + a3*wb[3*KV_+c0*9+tap0];
            float v1 = a0*wb[c1*9+tap1] + a1*wb[KV_+c1*9+tap1]
                     + a2*wb[2*KV_+c1*9+tap1] + a3*wb[3*KV_+c1*9+tap1];
            union { unsigned short u[2]; unsigned v; } pk;
            pk.u[0] = (unsigned short)f2bf(v0);
            pk.u[1] = (unsigned short)f2bf(v1);
            dst[ii] = pk.v;
        }
    }
}

// ---------------------------------------------------------------------------
// Kernel 4: LDS-staged implicit GEMM, BK=32 double-buffer with COUNTED vmcnt
// (T4). Same fragment mapping / LDS footprint (32 KB) / grid / swizzle as
// round-4; ONLY the sync structure changes:
//   __syncthreads (= s_waitcnt vmcnt(0) lgkmcnt(0); s_barrier) drained the
//   prefetch queue to 0 at EVERY barrier -> exposed ~full L2/HBM latency per
//   step at ~1.4 blocks/CU. Now: raw s_barrier + counted s_waitcnt vmcnt(4);
//   loads stay in flight across barriers (steady state 4-8 outstanding,
//   never 0 in the loop). m198 proved this keeps MFMA fed at 1 block/CU.
// Safety: each wave waits ITS vmcnt(4) before barrier-1 => barrier-1 proves
// ALL waves' current-buffer loads landed. lgkmcnt(0)+barrier-2 proves all
// ds_reads drained before any wave issues the overwriting stage.
// ---------------------------------------------------------------------------
__global__ __launch_bounds__(256) void dc_gemm(const short* __restrict__ Ws,
                                               const short* __restrict__ xTp,
                                               float* __restrict__ out) {
    // ---- bijective XCD swizzle over the flat 1600-block grid ----
    int orig = blockIdx.x;
    int swz  = (orig & 7) * 200 + (orig >> 3);   // 1600 % 8 == 0 -> bijective
    const int bx  = swz % 25;                    // n-block
    const int byz = swz / 25;
    const int by  = byz & 1;                     // m-block
    const int b   = byz >> 1;                    // sample

    const int m0 = by * 128;
    const int n0 = bx * 128;
    const int tid  = threadIdx.x;
    const int lane = tid & 63;
    const int wv   = tid >> 6;
    const int wm   = wv & 1, wn = wv >> 1;
    const int l16  = lane & 15, quad = lane >> 4;

    __shared__ short lA[2][4096];   // 2 x 8 KB
    __shared__ short lB[2][4096];   // 2 x 8 KB   (32 KB total)
    short* lAf = &lA[0][0];
    short* lBf = &lB[0][0];

    // wave wv stages regions t = 2*wv + j (j=0,1) for both A and B.
    const short* aG[2];
    const short* bG[2];
    int tOff[2];
    #pragma unroll
    for (int j = 0; j < 2; ++j) {
        int t = 2*wv + j;
        int row = t*16 + l16;
        aG[j] = Ws + ((size_t)b*OUT_ + m0 + row)*KV_ + quad*8;
        int n = n0 + row;
        int idc = min(n, HW_ - 1);
        int y = idc / W_, xx2 = idc - y * W_;
        int pbc = (y + 1) * PW_ + (xx2 + 1);
        bG[j] = xTp + ((size_t)b*PP_ + pbc)*C_ + quad*8;
        tOff[j] = t * 512;
    }

    int nidx[4];
    #pragma unroll
    for (int ni = 0; ni < 4; ++ni)
        nidx[ni] = n0 + wn*64 + ni*16 + l16;

    float4_t acc[4][4];
    #pragma unroll
    for (int mi = 0; mi < 4; ++mi)
        #pragma unroll
        for (int ni = 0; ni < 4; ++ni)
            acc[mi][ni] = (float4_t){0.f, 0.f, 0.f, 0.f};

    // stage sub-step ss (= tap*4 + kq2, 36 total) into buffer buf.
    // ka = tap*128 + (ss&3)*32 = ss*32; tap/3 via magic-mul (no v_div).
    auto stage = [&](int ss, int buf) {
        int tap = ss >> 2;
        int ty  = (tap * 11) >> 5;               // == tap/3 for tap in [0,8]
        int tx  = tap - 3 * ty;
        int doff = ((ty - 1) * PW_ + (tx - 1)) * C_;
        int ka = ss * 32;
        int cb = (ss & 3) * 32;
        short* la = lAf + buf * 4096;
        short* lb = lBf + buf * 4096;
        #pragma unroll
        for (int j = 0; j < 2; ++j) {
            gl_lds16(aG[j] + ka,        la + tOff[j]);
            gl_lds16(bG[j] + doff + cb, lb + tOff[j]);
        }
    };

    auto compute = [&](int buf) {
        const short* la = lAf + buf * 4096;
        const short* lb = lBf + buf * 4096;
        short8_t af[4], bfr[4];
        #pragma unroll
        for (int mi = 0; mi < 4; ++mi)
            af[mi] = *(const short8_t*)(la + (wm*4+mi)*512 + lane*8);
        #pragma unroll
        for (int ni = 0; ni < 4; ++ni)
            bfr[ni] = *(const short8_t*)(lb + (wn*4+ni)*512 + lane*8);
        #pragma unroll
        for (int mi = 0; mi < 4; ++mi)
            #pragma unroll
            for (int ni = 0; ni < 4; ++ni)
                acc[mi][ni] = __builtin_amdgcn_mfma_f32_16x16x32_bf16(
                    af[mi], bfr[ni], acc[mi][ni], 0, 0, 0);
    };

    // Prologue: 2 stages in flight (8 loads/wave).
    stage(0, 0);
    stage(1, 1);
    #pragma unroll 1
    for (int ss = 0; ss < 35; ++ss) {
        int buf = ss & 1;
        // my 4 oldest loads (current buf) landed; others may stay in flight
        asm volatile("s_waitcnt vmcnt(4)" ::: "memory");
        __builtin_amdgcn_s_barrier();            // => ALL waves' cur loads landed
        compute(buf);
        asm volatile("s_waitcnt lgkmcnt(0)" ::: "memory");
        __builtin_amdgcn_s_barrier();            // => ALL waves' reads drained
        if (ss < 34) stage(ss + 2, buf);         // overwrite now safe
    }
    // final sub-step (ss = 35): only its 4 loads remain in flight
    asm volatile("s_waitcnt vmcnt(0)" ::: "memory");
    __builtin_amdgcn_s_barrier();
    compute(1);

    // Epilogue: D[m = quad*4 + reg][n = l16] per 16x16 tile
    const size_t obase = (size_t)b * OUT_ * HW_;
    #pragma unroll
    for (int mi = 0; mi < 4; ++mi) {
        int m = m0 + wm*64 + mi*16 + quad*4;
        #pragma unroll
        for (int ni = 0; ni < 4; ++ni) {
            int n = nidx[ni];
            if (n < HW_) {
                float* op = out + obase + (size_t)m * HW_ + n;
                #pragma unroll
                for (int r = 0; r < 4; ++r)
                    op[(size_t)r * HW_] = acc[mi][ni][r];
            }
        }
    }
}

// ---------------------------------------------------------------------------
extern "C" void kernel_launch(void* const* d_in, const int* in_sizes, int n_in,
                              void* d_out, int out_size, void* d_ws, size_t ws_size,
                              hipStream_t stream) {
    const float* x    = (const float*)d_in[0];
    const float* bank = (const float*)d_in[1];
    const float* fc1w = (const float*)d_in[2];
    const float* fc1b = (const float*)d_in[3];
    const float* fc2w = (const float*)d_in[4];
    const float* fc2b = (const float*)d_in[5];
    float* out = (float*)d_out;

    char* ws = (char*)d_ws;
    float* pooled = (float*)ws;                          // 16 KB
    float* attn   = (float*)(ws + 16*1024);              // 512 B
    bf16*  Ws     = (bf16*) (ws + 32*1024);              // 18,874,368 B
    short* xTp    = (short*)(ws + 32*1024 + 18874368);   // 27,557,888 B

    dc_pool  <<<B_*C_, 256, 0, stream>>>(x, pooled);
    dc_xt    <<<dim3(27, B_), 256, 0, stream>>>(x, xTp);
    dc_attn  <<<B_,     64, 0, stream>>>(pooled, fc1w, fc1b, fc2w, fc2b, attn);
    dc_wsynth<<<dim3(OUT_, 4), 256, 0, stream>>>(bank, attn, Ws);
    dc_gemm  <<<dim3(1600), 256, 0, stream>>>((const short*)Ws, xTp, out);
}